// Round 1
// baseline (116.756 us; speedup 1.0000x reference)
//
#include <hip/hip_runtime.h>

// Reference math:
//   y        = x @ W.T + b                         (B, OUT)
//   m        = max(y, axis=1, keepdims=True)        (B, 1)
//   centered = m - mean(m, axis=1, keepdims=True)   == m - m == 0.0 exactly (finite inputs)
//   out      = gelu_tanh(0.0)                       == 0.0 exactly
// The GEMM is dead code; the output is out_size zeros (out_size = 4096 floats = 16 KB).
//
// Fastest correct implementation: a single memset node in the captured graph.
// hipMemsetAsync is graph-capture-safe (the harness's own reset() uses it), and
// byte-zero is bit-exact float 0.0f. This removes our kernel dispatch entirely:
// no wave launch, no grid-stride loop, no tail kernel.

// Fallback kernel kept for reference / future rounds (NOT launched): a single
// vec4 zero-fill dispatch, in case a future harness rejects memset nodes.
__global__ void ModelNew_25056839205334_zero(float4* __restrict__ out, int n4) {
    int i = blockIdx.x * blockDim.x + threadIdx.x;
    if (i < n4) out[i] = make_float4(0.0f, 0.0f, 0.0f, 0.0f);
}

extern "C" void kernel_launch(void* const* d_in, const int* in_sizes, int n_in,
                              void* d_out, int out_size, void* d_ws, size_t ws_size,
                              hipStream_t stream) {
    (void)d_in; (void)in_sizes; (void)n_in; (void)d_ws; (void)ws_size;

    // out_size is in float elements (prior verified kernel wrote exactly
    // out_size floats). Zero the whole output buffer with one memset node.
    hipMemsetAsync(d_out, 0, (size_t)out_size * sizeof(float), stream);
}